// Round 1
// baseline (71.193 us; speedup 1.0000x reference)
//
#include <hip/hip_runtime.h>
#include <hip/hip_bf16.h>

#define NPTS   300
#define HW_SZ  1920
#define TOTAL  (NPTS * HW_SZ)    // 576000
#define NCOL   2400              // columns c = n*8 + h
#define L2T128 0.10381025293350249f   // log2(10000)/128
#define KREVL2 3.9923601817f     // log2(100 / (2*pi)) -> angles in revolutions

#define BM   128
#define BN   48                  // 2400 / 48 = 50 exact -> grid 750 = ~3x256 CUs
#define LDK2 136                 // BsP/BsQ row stride (shorts)
#define SNP  132                 // snq/cnq row stride (floats)
#define WPP  132                 // wpk row stride (dwords)
#define MT   15                  // 1920 / 128
#define CT   50                  // 2400 / 48 (exact, no pad)

typedef __attribute__((ext_vector_type(8))) short short8;
typedef __attribute__((ext_vector_type(4))) float floatx4;

union frag_u { unsigned u[4]; short8 s; };

// pack two f32 -> bf16 pair (round-half-up): 2 v_add + 1 v_perm
__device__ __forceinline__ unsigned pk_bf16(float lo, float hi) {
    return __builtin_amdgcn_perm(__float_as_uint(hi) + 0x8000u,
                                 __float_as_uint(lo) + 0x8000u,
                                 0x07060302u);
}
__device__ __forceinline__ float blo(unsigned u) { return __uint_as_float(u << 16); }
__device__ __forceinline__ float bhi(unsigned u) { return __uint_as_float(u & 0xffff0000u); }

// All angles in REVOLUTIONS (krev = k/2pi, max |angle| = 248.4 rev < 256 domain):
// raw v_sin_f32 / v_cos_f32, one instruction each.
// out[hw, c] = relu( sum_i cos*P + sin*Q + b[h] );  P,Q from angle-addition.
// v17: BN 64->48 rebalance. Grid 750 ~= 3 blocks/CU exactly (was 570 @ 3-resident:
// +34% per-CU tail). 2400%48==0 kills the NCOL guard and the pad-n select.
__global__ __launch_bounds__(256, 3) void dre_v17(const float* __restrict__ pd,
                                                  const float* __restrict__ dm,
                                                  const float* __restrict__ W,
                                                  const float* __restrict__ b,
                                                  float* __restrict__ out)
{
    __shared__ float    kfr[128];            //  0.5 KB  krev[i]
    __shared__ float    ldm[BM];             //  0.5 KB
    __shared__ float    snq[6 * SNP];        //  3.1 KB  sin(krev_i lp(n)) [rev]
    __shared__ float    cnq[6 * SNP];        //  3.1 KB
    __shared__ unsigned wpk[8 * WPP];        //  4.2 KB  (bf16 ws | bf16 wc<<16)[h][i]
    __shared__ unsigned short BsP[BN * LDK2];// 12.75 KB
    __shared__ unsigned short BsQ[BN * LDK2];// 12.75 KB => ~36.9 KB, 3+ blk/CU

    const int tid = threadIdx.x;
    const int m0  = blockIdx.x * BM;
    const int c0  = blockIdx.y * BN;
    const int n0  = c0 >> 3;                 // block covers n0..n0+5

    // ---- setup (race-free: ldm[0..127] from tid 128..255 exactly) ----
    if (tid < 128) kfr[tid] = exp2f(KREVL2 - (float)tid * L2T128);
    else           ldm[tid - 128] = __logf(dm[m0 + tid - 128] + 1e-5f);
    {   // W -> packed bf16 pairs, transposed [h][i]
        const int h = tid & 7, i0 = (tid >> 3) * 4;
        unsigned pk[4];
#pragma unroll
        for (int j = 0; j < 4; ++j)
            pk[j] = pk_bf16(W[(i0 + j) * 16 + h], W[(i0 + j) * 16 + 8 + h]);
        *(uint4*)&wpk[h * WPP + i0] = make_uint4(pk[0], pk[1], pk[2], pk[3]);
    }
    {   // sn/cn for the block's 6 n's (angles in revolutions)
        const int nl = tid >> 5, i0 = (tid & 31) * 4;
        if (nl < 6) {
            const int nn = n0 + nl;                       // always < 300
            const float pv = pd[nn];
            const float lp = __logf(fmaxf(pv, 0.0f) + 1e-5f);
            float s[4], c[4];
#pragma unroll
            for (int j = 0; j < 4; ++j) {
                const float a = exp2f(KREVL2 - (float)(i0 + j) * L2T128) * lp;
                s[j] = __builtin_amdgcn_sinf(a);
                c[j] = __builtin_amdgcn_cosf(a);
            }
            *(float4*)&snq[nl * SNP + i0] = make_float4(s[0], s[1], s[2], s[3]);
            *(float4*)&cnq[nl * SNP + i0] = make_float4(c[0], c[1], c[2], c[3]);
        }
    }
    __syncthreads();

    // ---- build BsP / BsQ, full i in [0,128), one pass, 48 c-rows ----
    if (tid < 192) {
        const int bcr = tid >> 2, q = tid & 3;            // c row, 32-i span
        const int bnl = bcr >> 3, bh = bcr & 7;
#pragma unroll
        for (int half = 0; half < 2; ++half) {
            const int ib0 = q * 32 + half * 16;
            unsigned pp[8], qq[8];
#pragma unroll
            for (int g = 0; g < 4; ++g) {
                const int i4 = ib0 + g * 4;
                const float4 s4 = *(const float4*)&snq[bnl * SNP + i4];
                const float4 c4 = *(const float4*)&cnq[bnl * SNP + i4];
                const uint4  w4 = *(const uint4*)&wpk[bh * WPP + i4];
                const float ws0 = blo(w4.x), wc0 = bhi(w4.x);
                const float ws1 = blo(w4.y), wc1 = bhi(w4.y);
                const float ws2 = blo(w4.z), wc2 = bhi(w4.z);
                const float ws3 = blo(w4.w), wc3 = bhi(w4.w);
                const float P0 = ws0*s4.x + wc0*c4.x, Q0 = wc0*s4.x - ws0*c4.x;
                const float P1 = ws1*s4.y + wc1*c4.y, Q1 = wc1*s4.y - ws1*c4.y;
                const float P2 = ws2*s4.z + wc2*c4.z, Q2 = wc2*s4.z - ws2*c4.z;
                const float P3 = ws3*s4.w + wc3*c4.w, Q3 = wc3*s4.w - ws3*c4.w;
                pp[2*g] = pk_bf16(P0, P1);  pp[2*g+1] = pk_bf16(P2, P3);
                qq[2*g] = pk_bf16(Q0, Q1);  qq[2*g+1] = pk_bf16(Q2, Q3);
            }
            *(uint4*)&BsP[bcr * LDK2 + ib0]     = make_uint4(pp[0], pp[1], pp[2], pp[3]);
            *(uint4*)&BsP[bcr * LDK2 + ib0 + 8] = make_uint4(pp[4], pp[5], pp[6], pp[7]);
            *(uint4*)&BsQ[bcr * LDK2 + ib0]     = make_uint4(qq[0], qq[1], qq[2], qq[3]);
            *(uint4*)&BsQ[bcr * LDK2 + ib0 + 8] = make_uint4(qq[4], qq[5], qq[6], qq[7]);
        }
    }
    __syncthreads();

    // ---- MFMA phase: JIT A-frags, 48 MFMAs (2 M-subtiles x 3 N-frags), no barriers ----
    const int w = tid >> 6, lane = tid & 63, quad = lane >> 4, l16 = lane & 15;
    const float ldr0 = ldm[w * 32 + l16];
    const float ldr1 = ldm[w * 32 + 16 + l16];

    floatx4 acc[2][3];
#pragma unroll
    for (int mi = 0; mi < 2; ++mi)
#pragma unroll
        for (int nf = 0; nf < 3; ++nf) acc[mi][nf] = (floatx4){0.f, 0.f, 0.f, 0.f};

#pragma unroll
    for (int ib = 0; ib < 2; ++ib) {
        frag_u cf[2][2], sf[2][2];                        // [mi][ks]
#pragma unroll
        for (int ks = 0; ks < 2; ++ks) {
            const int kb = ib * 64 + ks * 32 + quad * 8;
            const float4 f0 = *(const float4*)&kfr[kb];
            const float4 f1 = *(const float4*)&kfr[kb + 4];
            const float fr[8] = {f0.x, f0.y, f0.z, f0.w, f1.x, f1.y, f1.z, f1.w};
            float s0[8], c0v[8], s1[8], c1v[8];
#pragma unroll
            for (int j = 0; j < 8; ++j) {
                const float a0 = fr[j] * ldr0;            // revolutions
                const float a1 = fr[j] * ldr1;
                s0[j]  = __builtin_amdgcn_sinf(a0);
                c0v[j] = __builtin_amdgcn_cosf(a0);
                s1[j]  = __builtin_amdgcn_sinf(a1);
                c1v[j] = __builtin_amdgcn_cosf(a1);
            }
#pragma unroll
            for (int r = 0; r < 4; ++r) {
                cf[0][ks].u[r] = pk_bf16(c0v[2*r], c0v[2*r+1]);
                sf[0][ks].u[r] = pk_bf16(s0[2*r],  s0[2*r+1]);
                cf[1][ks].u[r] = pk_bf16(c1v[2*r], c1v[2*r+1]);
                sf[1][ks].u[r] = pk_bf16(s1[2*r],  s1[2*r+1]);
            }
        }
#pragma unroll
        for (int ks = 0; ks < 2; ++ks) {
            const int koff = ib * 64 + ks * 32 + quad * 8;
#pragma unroll
            for (int nf = 0; nf < 3; ++nf) {
                short8 bp = *(const short8*)&BsP[(nf * 16 + l16) * LDK2 + koff];
                acc[0][nf] = __builtin_amdgcn_mfma_f32_16x16x32_bf16(cf[0][ks].s, bp, acc[0][nf], 0, 0, 0);
                acc[1][nf] = __builtin_amdgcn_mfma_f32_16x16x32_bf16(cf[1][ks].s, bp, acc[1][nf], 0, 0, 0);
                short8 bq = *(const short8*)&BsQ[(nf * 16 + l16) * LDK2 + koff];
                acc[0][nf] = __builtin_amdgcn_mfma_f32_16x16x32_bf16(sf[0][ks].s, bq, acc[0][nf], 0, 0, 0);
                acc[1][nf] = __builtin_amdgcn_mfma_f32_16x16x32_bf16(sf[1][ks].s, bq, acc[1][nf], 0, 0, 0);
            }
        }
    }

    // ---- epilogue (verified): C/D col=lane&15, row=quad*4+reg; no guards needed ----
    const float bias = b[lane & 7];
#pragma unroll
    for (int mi = 0; mi < 2; ++mi) {
#pragma unroll
        for (int nf = 0; nf < 3; ++nf) {
            const int c = c0 + nf * 16 + l16;             // always < 2400
            const int n = c >> 3, h = c & 7;
            const int hw = m0 + w * 32 + mi * 16 + quad * 4;
            floatx4 v = acc[mi][nf];
            v.x = fmaxf(v.x + bias, 0.0f);
            v.y = fmaxf(v.y + bias, 0.0f);
            v.z = fmaxf(v.z + bias, 0.0f);
            v.w = fmaxf(v.w + bias, 0.0f);
            *(floatx4*)(out + (size_t)h * TOTAL + (size_t)n * HW_SZ + hw) = v;
        }
    }
}

extern "C" void kernel_launch(void* const* d_in, const int* in_sizes, int n_in,
                              void* d_out, int out_size, void* d_ws, size_t ws_size,
                              hipStream_t stream) {
    const float* pd = (const float*)d_in[0];
    const float* dm = (const float*)d_in[1];
    const float* W  = (const float*)d_in[2];
    const float* b  = (const float*)d_in[3];
    float* out = (float*)d_out;

    dre_v17<<<dim3(MT, CT), 256, 0, stream>>>(pd, dm, W, b, out);
}